// Round 18
// baseline (314.416 us; speedup 1.0000x reference)
//
#include <hip/hip_runtime.h>
#include <hip/hip_bf16.h>
#include <stdint.h>

#define B_ 2
#define N_ 4096
#define C_ 512
#define H_ 8
#define D_ 64
#define M_ (B_*N_)     // 8192
#define K3_ (3*C_)     // 1536
#define NCH 4          // KV-split ways

typedef __attribute__((ext_vector_type(8)))  short short8;
typedef __attribute__((ext_vector_type(4)))  float f32x4;
typedef __attribute__((ext_vector_type(16))) float f32x16;

// ---------- helpers ----------
static __device__ __forceinline__ unsigned short f2bf(float f) {
  union { float f; unsigned u; } cv; cv.f = f;
  unsigned r = cv.u + 0x7fffu + ((cv.u >> 16) & 1u);   // RNE
  return (unsigned short)(r >> 16);
}
static __device__ __forceinline__ float bf2f(short x) {
  union { unsigned u; float f; } cv;
  cv.u = ((unsigned)(unsigned short)x) << 16;
  return cv.f;
}
static __device__ __forceinline__ float fexp2(float x) {
#if __has_builtin(__builtin_amdgcn_exp2f)
  return __builtin_amdgcn_exp2f(x);
#else
  return exp2f(x);
#endif
}
static __device__ __forceinline__ unsigned cvt_pk_bf16(float a, float b) {
  unsigned r;
  asm("v_cvt_pk_bf16_f32 %0, %1, %2" : "=v"(r) : "v"(a), "v"(b));
  return r;   // lo = bf16(a), hi = bf16(b)
}
static __device__ __forceinline__ void gload_lds16(const void* g, void* l) {
  __builtin_amdgcn_global_load_lds((const __attribute__((address_space(1))) unsigned*)g,
                                   (__attribute__((address_space(3))) unsigned*)l, 16, 0, 0);
}
static __device__ __forceinline__ f32x16 zero16() {
  f32x16 z;
#pragma unroll
  for (int i = 0; i < 16; i++) z[i] = 0.f;
  return z;
}

// ---------- prep: casts + rope table in one launch ----------
__global__ void prep(const float* __restrict__ x, const float* __restrict__ Wqkv,
                     const float* __restrict__ Wproj,
                     short* __restrict__ xb, short* __restrict__ wqkvb,
                     short* __restrict__ wprjb, float2* __restrict__ tab) {
  int blk = blockIdx.x, t = threadIdx.x;
  if (blk < 4096) {
    int i = blk * 256 + t;
    float4 v = ((const float4*)x)[i];
    short4 o;
    o.x = (short)f2bf(v.x); o.y = (short)f2bf(v.y);
    o.z = (short)f2bf(v.z); o.w = (short)f2bf(v.w);
    ((short4*)xb)[i] = o;
  } else if (blk < 4864) {
    int i = (blk - 4096) * 256 + t;
    float4 v = ((const float4*)Wqkv)[i];
    short4 o;
    o.x = (short)f2bf(v.x); o.y = (short)f2bf(v.y);
    o.z = (short)f2bf(v.z); o.w = (short)f2bf(v.w);
    ((short4*)wqkvb)[i] = o;
  } else if (blk < 5120) {
    int i = (blk - 4864) * 256 + t;
    float4 v = ((const float4*)Wproj)[i];
    short4 o;
    o.x = (short)f2bf(v.x); o.y = (short)f2bf(v.y);
    o.z = (short)f2bf(v.z); o.w = (short)f2bf(v.w);
    ((short4*)wprjb)[i] = o;
  } else {
    int i = (blk - 5120) * 256 + t;   // 4096*32
    int p = i & 31, n = i >> 5;
    float freq = exp2f(-((float)(2 * p) / 64.0f) * 13.287712379549449f);
    float ang = (float)n * freq;
    float s, c;
    sincosf(ang, &s, &c);
    float2 r; r.x = c; r.y = s;
    tab[i] = r;
  }
}

// ---------- rope (coalesced LDS-staged) + V frag transpose, one launch ----------
__global__ void rope_vt(const short* __restrict__ qkvb, const float2* __restrict__ tab,
                        short* __restrict__ Qf, short* __restrict__ Kf,
                        short* __restrict__ Vf) {
  __shared__ short tile[128][72];
  int blk = blockIdx.x, t = threadIdx.x;
  if (blk < 1024) {
    int tk = blk >> 9;
    int bh = (blk & 511) >> 5;
    int nb4 = blk & 31;
    int b = bh >> 3, h = bh & 7;
    int n0 = nb4 * 128;
#pragma unroll
    for (int pass = 0; pass < 4; pass++) {
      int row = pass * 32 + (t >> 3), chunk = t & 7;
      short8 v = *(const short8*)(qkvb + (size_t)(b * N_ + n0 + row) * K3_ + tk * C_ + h * D_ + chunk * 8);
      *(short8*)&tile[row][chunk * 8] = v;
    }
    __syncthreads();
    int lane = t & 63, f = t >> 6;
    int c = lane & 31, hi = lane >> 5;
    int d0 = f * 16 + hi * 8;
    float sc = (tk == 0) ? 0.18033688011112042f : 1.0f;  // SCALE * log2(e) on Q
    short* base = (tk ? Kf : Qf);
#pragma unroll
    for (int i = 0; i < 4; i++) {
      int n_l = i * 32 + c;
      short8 v = *(const short8*)&tile[n_l][d0];
      const float2* tp = tab + (size_t)(n0 + n_l) * 32 + (d0 >> 1);
      short8 w;
#pragma unroll
      for (int j = 0; j < 4; j++) {
        float e = bf2f(v[2 * j]), o = bf2f(v[2 * j + 1]);
        float2 cs = tp[j];
        float e2 = (e * cs.x - o * cs.y) * sc;
        float o2 = (e * cs.y + o * cs.x) * sc;
        w[2 * j] = (short)f2bf(e2);
        w[2 * j + 1] = (short)f2bf(o2);
      }
      short* dst = base + (((size_t)(bh * 128 + nb4 * 4 + i) * 4 + f) * 512) + lane * 8;
      *(short8*)dst = w;
    }
  } else {
    int blk2 = blk - 1024;             // 2048
    int bh = blk2 >> 7, kblk = blk2 & 127;
    int b = bh >> 3, h = bh & 7;
    int n0 = kblk * 32;
    {
      int row = t >> 3, c8 = t & 7;
      short8 v = *(const short8*)(qkvb + (size_t)(b * N_ + n0 + row) * K3_ + 2 * C_ + h * D_ + c8 * 8);
      *(short8*)&tile[row][c8 * 8] = v;
    }
    __syncthreads();
    {
      int frag = t >> 6, lane = t & 63;
      int hi = lane >> 5, c = lane & 31;
      int g = frag & 1, dblk = frag >> 1;
      short8 w;
#pragma unroll
      for (int j = 0; j < 8; j++) w[j] = tile[g * 16 + hi * 8 + j][dblk * 32 + c];
      *(short8*)(Vf + ((size_t)(bh * 128 + kblk) * 4 + frag) * 512 + lane * 8) = w;
    }
  }
}

// ---------- GEMM (qkv): BK=64, XOR-swizzled LDS, 4 m-frags/wave ----------
__global__ __launch_bounds__(256) void gemm_qkv(const short* __restrict__ A, const short* __restrict__ Bw,
                                                const float* __restrict__ bias, short* __restrict__ Cout,
                                                int M, int Nout, int K) {
  __shared__ short As[4 * 32 * 64];
  __shared__ short Bs[128 * 64];
  int t = threadIdx.x, lane = t & 63, w = t >> 6, wr = w >> 1, wc = w & 1;
  int tM = blockIdx.x * 128, tN = blockIdx.y * 128;
  int lrow = lane & 15, lhi = lane >> 4;
  int rs = (lrow & 7) * 8;
  f32x4 acc[4][4];
#pragma unroll
  for (int fm = 0; fm < 4; fm++)
#pragma unroll
    for (int fn = 0; fn < 4; fn++)
#pragma unroll
      for (int r = 0; r < 4; r++) acc[fm][fn][r] = 0.f;

  int srow = t >> 3;
  int sq = ((t & 7) * 8) ^ ((srow & 7) * 8);

  for (int k0 = 0; k0 < K; k0 += 64) {
#pragma unroll
    for (int p = 0; p < 4; p++)
      gload_lds16(A + (size_t)(tM + p * 32 + srow) * K + k0 + sq, As + p * 2048 + t * 8);
#pragma unroll
    for (int p = 0; p < 4; p++)
      gload_lds16(Bw + (size_t)(tN + p * 32 + srow) * K + k0 + sq, Bs + p * 2048 + t * 8);
    __syncthreads();
#pragma unroll
    for (int kk = 0; kk < 2; kk++) {
      int ko = (kk * 32 + lhi * 8) ^ rs;
      short8 af[4], bfr[4];
#pragma unroll
      for (int f = 0; f < 4; f++)
        af[f] = *(const short8*)(As + (wr * 64 + f * 16 + lrow) * 64 + ko);
#pragma unroll
      for (int f = 0; f < 4; f++)
        bfr[f] = *(const short8*)(Bs + (wc * 64 + f * 16 + lrow) * 64 + ko);
#pragma unroll
      for (int fm = 0; fm < 4; fm++)
#pragma unroll
        for (int fn = 0; fn < 4; fn++)
          acc[fm][fn] = __builtin_amdgcn_mfma_f32_16x16x32_bf16(af[fm], bfr[fn], acc[fm][fn], 0, 0, 0);
    }
    __syncthreads();
  }

#pragma unroll
  for (int fn = 0; fn < 4; fn++) {
    int col = tN + wc * 64 + fn * 16 + lrow;
    float bv = bias[col];
#pragma unroll
    for (int fm = 0; fm < 4; fm++) {
      int row0 = tM + wr * 64 + fm * 16 + lhi * 4;
#pragma unroll
      for (int r = 0; r < 4; r++) {
        float v = acc[fm][fn][r] + bv;
        Cout[(size_t)(row0 + r) * Nout + col] = (short)f2bf(v);
      }
    }
  }
}

// ---------- proj GEMM with fused combine: A = (sum Op[ch]) * inv(l), staged via regs ----------
__global__ __launch_bounds__(256) void gemm_proj(const short* __restrict__ Op, const float* __restrict__ lp,
                                                 const short* __restrict__ Bw, const float* __restrict__ bias,
                                                 float* __restrict__ Cout) {
  __shared__ short As[2 * 32 * 64];
  __shared__ short Bs[128 * 64];
  const size_t chs = (size_t)16 * N_ * D_;
  int t = threadIdx.x, lane = t & 63, w = t >> 6, wr = w >> 1, wc = w & 1;
  int tM = blockIdx.x * 64, tN = blockIdx.y * 128;
  int lrow = lane & 15, lhi = lane >> 4;
  int rs = (lrow & 7) * 8;
  f32x4 acc[2][4];
#pragma unroll
  for (int fm = 0; fm < 2; fm++)
#pragma unroll
    for (int fn = 0; fn < 4; fn++)
#pragma unroll
      for (int r = 0; r < 4; r++) acc[fm][fn][r] = 0.f;

  int srow = t >> 3;
  int sq = ((t & 7) * 8) ^ ((srow & 7) * 8);   // d offset within head, [0,64)

  for (int k0 = 0; k0 < C_; k0 += 64) {
    int h = k0 >> 6;
    // fused A staging: sum NCH partials, normalize, write to swizzled LDS slot
#pragma unroll
    for (int p = 0; p < 2; p++) {
      int m = tM + p * 32 + srow;
      int b = m >> 12, q = m & (N_ - 1);
      size_t lidx = (size_t)(b * H_ + h) * N_ + q;
      size_t obase = ((size_t)(b * H_ + h) * N_ + q) * D_ + sq;
      float av[8];
#pragma unroll
      for (int j = 0; j < 8; j++) av[j] = 0.f;
      float l = 0.f;
#pragma unroll
      for (int chv = 0; chv < NCH; chv++) {
        short8 v = *(const short8*)(Op + chv * chs + obase);
#pragma unroll
        for (int j = 0; j < 8; j++) av[j] += bf2f(v[j]);
        l += lp[(size_t)chv * 16 * N_ + lidx];
      }
      float inv = 1.0f / l;
      short8 wv;
#pragma unroll
      for (int j = 0; j < 8; j++) wv[j] = (short)f2bf(av[j] * inv);
      *(short8*)(As + p * 2048 + t * 8) = wv;
    }
#pragma unroll
    for (int p = 0; p < 4; p++)
      gload_lds16(Bw + (size_t)(tN + p * 32 + srow) * C_ + k0 + sq, Bs + p * 2048 + t * 8);
    __syncthreads();
#pragma unroll
    for (int kk = 0; kk < 2; kk++) {
      int ko = (kk * 32 + lhi * 8) ^ rs;
      short8 af[2], bfr[4];
#pragma unroll
      for (int f = 0; f < 2; f++)
        af[f] = *(const short8*)(As + (wr * 32 + f * 16 + lrow) * 64 + ko);
#pragma unroll
      for (int f = 0; f < 4; f++)
        bfr[f] = *(const short8*)(Bs + (wc * 64 + f * 16 + lrow) * 64 + ko);
#pragma unroll
      for (int fm = 0; fm < 2; fm++)
#pragma unroll
        for (int fn = 0; fn < 4; fn++)
          acc[fm][fn] = __builtin_amdgcn_mfma_f32_16x16x32_bf16(af[fm], bfr[fn], acc[fm][fn], 0, 0, 0);
    }
    __syncthreads();
  }

#pragma unroll
  for (int fn = 0; fn < 4; fn++) {
    int col = tN + wc * 64 + fn * 16 + lrow;
    float bv = bias[col];
#pragma unroll
    for (int fm = 0; fm < 2; fm++) {
      int row0 = tM + wr * 32 + fm * 16 + lhi * 4;
#pragma unroll
      for (int r = 0; r < 4; r++)
        Cout[(size_t)(row0 + r) * C_ + col] = acc[fm][fn][r] + bv;
    }
  }
}

// ---------- attn building blocks ----------
static __device__ __forceinline__ f32x16 qk4(const short8* k, const short8* q, const f32x16& z0) {
  __builtin_amdgcn_s_setprio(1);
  f32x16 st = __builtin_amdgcn_mfma_f32_32x32x16_bf16(k[0], q[0], z0, 0, 0, 0);
  st = __builtin_amdgcn_mfma_f32_32x32x16_bf16(k[1], q[1], st, 0, 0, 0);
  st = __builtin_amdgcn_mfma_f32_32x32x16_bf16(k[2], q[2], st, 0, 0, 0);
  st = __builtin_amdgcn_mfma_f32_32x32x16_bf16(k[3], q[3], st, 0, 0, 0);
  __builtin_amdgcn_s_setprio(0);
  return st;
}
static __device__ __forceinline__ void soft_pv(const f32x16& st, const short8* v,
                                               f32x16& o0, f32x16& o1, float& lsum) {
  float ls = 0.f;
  unsigned cpk[8];
#pragma unroll
  for (int q2 = 0; q2 < 4; q2++) {
    float e0 = fexp2(st[4 * q2]),     e1 = fexp2(st[4 * q2 + 1]);
    float e2 = fexp2(st[4 * q2 + 2]), e3 = fexp2(st[4 * q2 + 3]);
    ls += (e0 + e1) + (e2 + e3);
    cpk[2 * q2]     = cvt_pk_bf16(e0, e1);
    cpk[2 * q2 + 1] = cvt_pk_bf16(e2, e3);
  }
  lsum += ls;
  unsigned w00 = cpk[0], w02 = cpk[2];
  asm volatile("v_permlane32_swap_b32 %0, %1" : "+v"(w00), "+v"(w02));
  unsigned w01 = cpk[1], w03 = cpk[3];
  asm volatile("v_permlane32_swap_b32 %0, %1" : "+v"(w01), "+v"(w03));
  unsigned w10 = cpk[4], w12 = cpk[6];
  asm volatile("v_permlane32_swap_b32 %0, %1" : "+v"(w10), "+v"(w12));
  unsigned w11 = cpk[5], w13 = cpk[7];
  asm volatile("v_permlane32_swap_b32 %0, %1" : "+v"(w11), "+v"(w13));
  union { unsigned u[4]; short8 s; } u0, u1;
  u0.u[0] = w00; u0.u[1] = w01; u0.u[2] = w02; u0.u[3] = w03;
  u1.u[0] = w10; u1.u[1] = w11; u1.u[2] = w12; u1.u[3] = w13;
  __builtin_amdgcn_s_setprio(1);
  o0 = __builtin_amdgcn_mfma_f32_32x32x16_bf16(u0.s, v[0], o0, 0, 0, 0);
  o0 = __builtin_amdgcn_mfma_f32_32x32x16_bf16(u1.s, v[1], o0, 0, 0, 0);
  o1 = __builtin_amdgcn_mfma_f32_32x32x16_bf16(u0.s, v[2], o1, 0, 0, 0);
  o1 = __builtin_amdgcn_mfma_f32_32x32x16_bf16(u1.s, v[3], o1, 0, 0, 0);
  __builtin_amdgcn_s_setprio(0);
}

// ---------- Flash attention: 64 q-rows/wave, reg-cap 170 (3 waves/SIMD), 4-way KV split ----------
__global__ __launch_bounds__(256, 3) void attn(const short* __restrict__ Qf, const short* __restrict__ Kf,
                                               const short* __restrict__ Vf,
                                               short* __restrict__ Op, float* __restrict__ lp) {
  __shared__ short Ks[2][4096];
  __shared__ short Vs[2][4096];
  int bh = blockIdx.x;
  int ch = blockIdx.z;
  int t = threadIdx.x;
  int wv = t >> 6, lane = t & 63;
  int c = lane & 31, hi = lane >> 5;
  int q0 = blockIdx.y * 256 + wv * 64;       // this wave: q0..q0+63
  const int nkb2 = N_ / (NCH * 64);          // 16 iters of 64 kv
  int kb0 = ch * (N_ / (NCH * 32));          // in 32-kv block units

  const short* QbA = Qf + ((size_t)(bh * 128 + (q0 >> 5)) * 4) * 512 + lane * 8;
  const short* Kg = Kf + ((size_t)(bh * 128 + kb0) * 4) * 512 + t * 8;
  const short* Vg = Vf + ((size_t)(bh * 128 + kb0) * 4) * 512 + t * 8;

  short8 qA[4], qB[4];
#pragma unroll
  for (int f = 0; f < 4; f++) qA[f] = *(const short8*)(QbA + f * 512);
#pragma unroll
  for (int f = 0; f < 4; f++) qB[f] = *(const short8*)(QbA + (4 + f) * 512);

  const f32x16 z0 = zero16();
  f32x16 oA0 = z0, oA1 = z0;
  f32x16 oB0 = z0, oB1 = z0;
  float lsA = 0.f, lsB = 0.f;

  gload_lds16(Kg,        &Ks[0][t * 8]);
  gload_lds16(Kg + 2048, &Ks[0][2048 + t * 8]);
  gload_lds16(Vg,        &Vs[0][t * 8]);
  gload_lds16(Vg + 2048, &Vs[0][2048 + t * 8]);
  __syncthreads();

  int buf = 0;
  for (int it = 0; it < nkb2; ++it) {
    if (it + 1 < nkb2) {
      const short* Kn = Kg + (size_t)(it + 1) * 4096;
      const short* Vn = Vg + (size_t)(it + 1) * 4096;
      gload_lds16(Kn,        &Ks[buf ^ 1][t * 8]);
      gload_lds16(Kn + 2048, &Ks[buf ^ 1][2048 + t * 8]);
      gload_lds16(Vn,        &Vs[buf ^ 1][t * 8]);
      gload_lds16(Vn + 2048, &Vs[buf ^ 1][2048 + t * 8]);
    }
#pragma unroll
    for (int s = 0; s < 2; s++) {
      short8 kf[4], vf[4];
#pragma unroll
      for (int f = 0; f < 4; f++) kf[f] = *(const short8*)&Ks[buf][s * 2048 + f * 512 + lane * 8];
#pragma unroll
      for (int f = 0; f < 4; f++) vf[f] = *(const short8*)&Vs[buf][s * 2048 + f * 512 + lane * 8];
      f32x16 stA = qk4(kf, qA, z0);
      f32x16 stB = qk4(kf, qB, z0);
      soft_pv(stA, vf, oA0, oA1, lsA);
      soft_pv(stB, vf, oB0, oB1, lsB);
    }
    __syncthreads();
    buf ^= 1;
  }

  float ltA = lsA + __shfl_xor(lsA, 32);
  float ltB = lsB + __shfl_xor(lsB, 32);
  float* lrow = lp + ((size_t)ch * 16 + bh) * N_ + q0;
  short* obase = Op + ((size_t)ch * 16 + bh) * N_ * D_;
  if (hi == 0) {
    lrow[c] = ltA;
    lrow[32 + c] = ltB;
  }
#pragma unroll
  for (int r = 0; r < 16; r++) {
    int ql = (r & 3) + 8 * (r >> 2) + 4 * hi;
    size_t nA = (size_t)(q0 + ql) * D_;
    size_t nB = (size_t)(q0 + 32 + ql) * D_;
    obase[nA + c]      = (short)f2bf(oA0[r]);
    obase[nA + 32 + c] = (short)f2bf(oA1[r]);
    obase[nB + c]      = (short)f2bf(oB0[r]);
    obase[nB + 32 + c] = (short)f2bf(oB1[r]);
  }
}

// ---------- launch ----------
extern "C" void kernel_launch(void* const* d_in, const int* in_sizes, int n_in,
                              void* d_out, int out_size, void* d_ws, size_t ws_size,
                              hipStream_t stream) {
  const float* x     = (const float*)d_in[0];
  const float* Wqkv  = (const float*)d_in[1];
  const float* bqkv  = (const float*)d_in[2];
  const float* Wproj = (const float*)d_in[3];
  const float* bproj = (const float*)d_in[4];
  float* out = (float*)d_out;
  char* ws = (char*)d_ws;

  // persistent region
  const size_t off_wprjb = 0;          // 524,288
  const size_t off_tab   = 524288;     // 1,048,576
  const size_t off_q     = 1572864;    // 8,388,608
  const size_t off_k     = 9961472;    // 8,388,608
  const size_t off_vt    = 18350080;   // 8,388,608 -> ends 26,738,688
  // phase-1 transient (aliased below by partials)
  const size_t off_xb    = 35127296;   // 8,388,608
  const size_t off_wqkvb = 43515904;   // 1,572,864
  const size_t off_qkvb  = 45088768;   // 25,165,824 -> ends 70,254,592
  // attn-phase partials (alias xb/wqkvb/qkvb)
  const size_t off_op    = 35127296;   // 4*16*4096*64*2 = 33,554,432
  const size_t off_l     = 68681728;   // 4*16*4096*4    =  1,048,576 -> ends 69,730,304
  if (ws_size < 70254592) return;

  short* xb    = (short*)(ws + off_xb);
  short* wqkvb = (short*)(ws + off_wqkvb);
  short* wprjb = (short*)(ws + off_wprjb);
  short* qkvb  = (short*)(ws + off_qkvb);
  short* Qfp   = (short*)(ws + off_q);
  short* Kfp   = (short*)(ws + off_k);
  short* Vfp   = (short*)(ws + off_vt);
  float2* tab  = (float2*)(ws + off_tab);
  short* Opp   = (short*)(ws + off_op);
  float* lpp   = (float*)(ws + off_l);

  prep<<<dim3(5632), dim3(256), 0, stream>>>(x, Wqkv, Wproj, xb, wqkvb, wprjb, tab);

  gemm_qkv<<<dim3(64, 12), dim3(256), 0, stream>>>(xb, wqkvb, bqkv, qkvb, M_, K3_, C_);

  rope_vt<<<dim3(3072), dim3(256), 0, stream>>>(qkvb, tab, Qfp, Kfp, Vfp);

  attn<<<dim3(16, 16, NCH), dim3(256), 0, stream>>>(Qfp, Kfp, Vfp, Opp, lpp);

  gemm_proj<<<dim3(128, 4), dim3(256), 0, stream>>>(Opp, lpp, wprjb, bproj, out);
}

// Round 19
// 125.562 us; speedup vs baseline: 2.5041x; 2.5041x over previous
//
#include <hip/hip_runtime.h>
#include <hip/hip_bf16.h>
#include <stdint.h>

#define B_ 2
#define N_ 4096
#define C_ 512
#define H_ 8
#define D_ 64
#define M_ (B_*N_)     // 8192
#define K3_ (3*C_)     // 1536
#define NCH 2          // KV-split ways

typedef __attribute__((ext_vector_type(8)))  short short8;
typedef __attribute__((ext_vector_type(4)))  float f32x4;
typedef __attribute__((ext_vector_type(16))) float f32x16;

// ---------- helpers ----------
static __device__ __forceinline__ unsigned short f2bf(float f) {
  union { float f; unsigned u; } cv; cv.f = f;
  unsigned r = cv.u + 0x7fffu + ((cv.u >> 16) & 1u);   // RNE
  return (unsigned short)(r >> 16);
}
static __device__ __forceinline__ float bf2f(short x) {
  union { unsigned u; float f; } cv;
  cv.u = ((unsigned)(unsigned short)x) << 16;
  return cv.f;
}
static __device__ __forceinline__ float fexp2(float x) {
#if __has_builtin(__builtin_amdgcn_exp2f)
  return __builtin_amdgcn_exp2f(x);
#else
  return exp2f(x);
#endif
}
static __device__ __forceinline__ unsigned cvt_pk_bf16(float a, float b) {
  unsigned r;
  asm("v_cvt_pk_bf16_f32 %0, %1, %2" : "=v"(r) : "v"(a), "v"(b));
  return r;   // lo = bf16(a), hi = bf16(b)
}
static __device__ __forceinline__ void gload_lds16(const void* g, void* l) {
  __builtin_amdgcn_global_load_lds((const __attribute__((address_space(1))) unsigned*)g,
                                   (__attribute__((address_space(3))) unsigned*)l, 16, 0, 0);
}
static __device__ __forceinline__ f32x16 zero16() {
  f32x16 z;
#pragma unroll
  for (int i = 0; i < 16; i++) z[i] = 0.f;
  return z;
}

// ---------- prep: casts + rope table in one launch ----------
__global__ void prep(const float* __restrict__ x, const float* __restrict__ Wqkv,
                     const float* __restrict__ Wproj,
                     short* __restrict__ xb, short* __restrict__ wqkvb,
                     short* __restrict__ wprjb, float2* __restrict__ tab) {
  int blk = blockIdx.x, t = threadIdx.x;
  if (blk < 4096) {
    int i = blk * 256 + t;
    float4 v = ((const float4*)x)[i];
    short4 o;
    o.x = (short)f2bf(v.x); o.y = (short)f2bf(v.y);
    o.z = (short)f2bf(v.z); o.w = (short)f2bf(v.w);
    ((short4*)xb)[i] = o;
  } else if (blk < 4864) {
    int i = (blk - 4096) * 256 + t;
    float4 v = ((const float4*)Wqkv)[i];
    short4 o;
    o.x = (short)f2bf(v.x); o.y = (short)f2bf(v.y);
    o.z = (short)f2bf(v.z); o.w = (short)f2bf(v.w);
    ((short4*)wqkvb)[i] = o;
  } else if (blk < 5120) {
    int i = (blk - 4864) * 256 + t;
    float4 v = ((const float4*)Wproj)[i];
    short4 o;
    o.x = (short)f2bf(v.x); o.y = (short)f2bf(v.y);
    o.z = (short)f2bf(v.z); o.w = (short)f2bf(v.w);
    ((short4*)wprjb)[i] = o;
  } else {
    int i = (blk - 5120) * 256 + t;   // 4096*32
    int p = i & 31, n = i >> 5;
    float freq = exp2f(-((float)(2 * p) / 64.0f) * 13.287712379549449f);
    float ang = (float)n * freq;
    float s, c;
    sincosf(ang, &s, &c);
    float2 r; r.x = c; r.y = s;
    tab[i] = r;
  }
}

// ---------- GEMM (qkv) with fused RoPE + fragment-layout epilogue ----------
// grid (64, 12): y<4 -> Q cols, y<8 -> K cols, else V cols.
__global__ __launch_bounds__(256) void gemm_qkv(const short* __restrict__ A, const short* __restrict__ Bw,
                                                const float* __restrict__ bias, const float2* __restrict__ tab,
                                                short* __restrict__ Qf, short* __restrict__ Kf,
                                                short* __restrict__ Vf) {
  __shared__ short As[4 * 32 * 64];
  __shared__ short Bs[128 * 64];
  const int K = C_;
  int t = threadIdx.x, lane = t & 63, w = t >> 6, wr = w >> 1, wc = w & 1;
  int tM = blockIdx.x * 128, tN = blockIdx.y * 128;
  int lrow = lane & 15, lhi = lane >> 4;
  int rs = (lrow & 7) * 8;
  f32x4 acc[4][4];
#pragma unroll
  for (int fm = 0; fm < 4; fm++)
#pragma unroll
    for (int fn = 0; fn < 4; fn++)
#pragma unroll
      for (int r = 0; r < 4; r++) acc[fm][fn][r] = 0.f;

  int srow = t >> 3;
  int sq = ((t & 7) * 8) ^ ((srow & 7) * 8);

  for (int k0 = 0; k0 < K; k0 += 64) {
#pragma unroll
    for (int p = 0; p < 4; p++)
      gload_lds16(A + (size_t)(tM + p * 32 + srow) * K + k0 + sq, As + p * 2048 + t * 8);
#pragma unroll
    for (int p = 0; p < 4; p++)
      gload_lds16(Bw + (size_t)(tN + p * 32 + srow) * K + k0 + sq, Bs + p * 2048 + t * 8);
    __syncthreads();
#pragma unroll
    for (int kk = 0; kk < 2; kk++) {
      int ko = (kk * 32 + lhi * 8) ^ rs;
      short8 af[4], bfr[4];
#pragma unroll
      for (int f = 0; f < 4; f++)
        af[f] = *(const short8*)(As + (wr * 64 + f * 16 + lrow) * 64 + ko);
#pragma unroll
      for (int f = 0; f < 4; f++)
        bfr[f] = *(const short8*)(Bs + (wc * 64 + f * 16 + lrow) * 64 + ko);
#pragma unroll
      for (int fm = 0; fm < 4; fm++)
#pragma unroll
        for (int fn = 0; fn < 4; fn++)
          acc[fm][fn] = __builtin_amdgcn_mfma_f32_16x16x32_bf16(af[fm], bfr[fn], acc[fm][fn], 0, 0, 0);
    }
    __syncthreads();
  }

  if (blockIdx.y < 8) {
    // ---- Q/K epilogue: bias + RoPE + frag-layout store ----
#pragma unroll
    for (int fn = 0; fn < 4; fn++) {
      int col = tN + wc * 64 + fn * 16 + lrow;
      float bv = bias[col];
      int tk = col >> 9;                 // 0 = Q, 1 = K (uniform per block)
      int h = (col >> 6) & 7;
      int d = col & 63;
      float sc = tk ? 1.0f : 0.18033688011112042f;   // SCALE * log2(e) on Q
      short* basep = tk ? Kf : Qf;
      bool even = ((d & 1) == 0);
#pragma unroll
      for (int fm = 0; fm < 4; fm++) {
#pragma unroll
        for (int r = 0; r < 4; r++) {
          int m = tM + wr * 64 + fm * 16 + lhi * 4 + r;
          int b = m >> 12, n = m & (N_ - 1);
          float v = acc[fm][fn][r] + bv;
          float pv = __shfl_xor(v, 1);
          float2 cs = tab[(size_t)n * 32 + (d >> 1)];
          float e = even ? v : pv, o = even ? pv : v;
          float outv = (even ? (e * cs.x - o * cs.y) : (e * cs.y + o * cs.x)) * sc;
          size_t flat = ((size_t)(((b * H_ + h) * 128 + (n >> 5)) * 4 + (d >> 4))) * 512
                        + ((d >> 3) & 1) * 256 + (n & 31) * 8 + (d & 7);
          basep[flat] = (short)f2bf(outv);
        }
      }
    }
  } else {
    // ---- V epilogue: bias + frag-layout store (short4-packed) ----
#pragma unroll
    for (int fn = 0; fn < 4; fn++) {
      int col = tN + wc * 64 + fn * 16 + lrow;
      float bv = bias[col];
      int h = (col >> 6) & 7;
      int d = col & 63;
#pragma unroll
      for (int fm = 0; fm < 4; fm++) {
        int m0 = tM + wr * 64 + fm * 16 + lhi * 4;
        int b = m0 >> 12, n0 = m0 & (N_ - 1);
        size_t flat0 = ((size_t)(((b * H_ + h) * 128 + (n0 >> 5)) * 4 + (d >> 5) * 2 + ((n0 >> 4) & 1))) * 512
                       + ((n0 >> 3) & 1) * 256 + (d & 31) * 8 + (n0 & 7);
        short4 w4;
        w4.x = (short)f2bf(acc[fm][fn][0] + bv);
        w4.y = (short)f2bf(acc[fm][fn][1] + bv);
        w4.z = (short)f2bf(acc[fm][fn][2] + bv);
        w4.w = (short)f2bf(acc[fm][fn][3] + bv);
        *(short4*)(Vf + flat0) = w4;
      }
    }
  }
}

// ---------- proj GEMM with fused combine: A = (Op[0]+Op[1]) * inv(l), staged via regs ----------
__global__ __launch_bounds__(256) void gemm_proj(const short* __restrict__ Op, const float* __restrict__ lp,
                                                 const short* __restrict__ Bw, const float* __restrict__ bias,
                                                 float* __restrict__ Cout) {
  __shared__ short As[2 * 32 * 64];
  __shared__ short Bs[128 * 64];
  const size_t chs = (size_t)16 * N_ * D_;
  int t = threadIdx.x, lane = t & 63, w = t >> 6, wr = w >> 1, wc = w & 1;
  int tM = blockIdx.x * 64, tN = blockIdx.y * 128;
  int lrow = lane & 15, lhi = lane >> 4;
  int rs = (lrow & 7) * 8;
  f32x4 acc[2][4];
#pragma unroll
  for (int fm = 0; fm < 2; fm++)
#pragma unroll
    for (int fn = 0; fn < 4; fn++)
#pragma unroll
      for (int r = 0; r < 4; r++) acc[fm][fn][r] = 0.f;

  int srow = t >> 3;
  int sq = ((t & 7) * 8) ^ ((srow & 7) * 8);   // d offset within head, [0,64)

  for (int k0 = 0; k0 < C_; k0 += 64) {
    int h = k0 >> 6;
#pragma unroll
    for (int p = 0; p < 2; p++) {
      int m = tM + p * 32 + srow;
      int b = m >> 12, q = m & (N_ - 1);
      size_t lidx = (size_t)(b * H_ + h) * N_ + q;
      float l = lp[lidx] + lp[(size_t)16 * N_ + lidx];
      float inv = 1.0f / l;
      size_t obase = ((size_t)(b * H_ + h) * N_ + q) * D_ + sq;
      short8 v0 = *(const short8*)(Op + obase);
      short8 v1 = *(const short8*)(Op + chs + obase);
      short8 wv;
#pragma unroll
      for (int j = 0; j < 8; j++) wv[j] = (short)f2bf((bf2f(v0[j]) + bf2f(v1[j])) * inv);
      *(short8*)(As + p * 2048 + t * 8) = wv;
    }
#pragma unroll
    for (int p = 0; p < 4; p++)
      gload_lds16(Bw + (size_t)(tN + p * 32 + srow) * C_ + k0 + sq, Bs + p * 2048 + t * 8);
    __syncthreads();
#pragma unroll
    for (int kk = 0; kk < 2; kk++) {
      int ko = (kk * 32 + lhi * 8) ^ rs;
      short8 af[2], bfr[4];
#pragma unroll
      for (int f = 0; f < 2; f++)
        af[f] = *(const short8*)(As + (wr * 32 + f * 16 + lrow) * 64 + ko);
#pragma unroll
      for (int f = 0; f < 4; f++)
        bfr[f] = *(const short8*)(Bs + (wc * 64 + f * 16 + lrow) * 64 + ko);
#pragma unroll
      for (int fm = 0; fm < 2; fm++)
#pragma unroll
        for (int fn = 0; fn < 4; fn++)
          acc[fm][fn] = __builtin_amdgcn_mfma_f32_16x16x32_bf16(af[fm], bfr[fn], acc[fm][fn], 0, 0, 0);
    }
    __syncthreads();
  }

#pragma unroll
  for (int fn = 0; fn < 4; fn++) {
    int col = tN + wc * 64 + fn * 16 + lrow;
    float bv = bias[col];
#pragma unroll
    for (int fm = 0; fm < 2; fm++) {
      int row0 = tM + wr * 32 + fm * 16 + lhi * 4;
#pragma unroll
      for (int r = 0; r < 4; r++)
        Cout[(size_t)(row0 + r) * C_ + col] = acc[fm][fn][r] + bv;
    }
  }
}

// ---------- attn building blocks ----------
static __device__ __forceinline__ f32x16 qk4(const short8* k, const short8* q, const f32x16& z0) {
  __builtin_amdgcn_s_setprio(1);
  f32x16 st = __builtin_amdgcn_mfma_f32_32x32x16_bf16(k[0], q[0], z0, 0, 0, 0);
  st = __builtin_amdgcn_mfma_f32_32x32x16_bf16(k[1], q[1], st, 0, 0, 0);
  st = __builtin_amdgcn_mfma_f32_32x32x16_bf16(k[2], q[2], st, 0, 0, 0);
  st = __builtin_amdgcn_mfma_f32_32x32x16_bf16(k[3], q[3], st, 0, 0, 0);
  __builtin_amdgcn_s_setprio(0);
  return st;
}
static __device__ __forceinline__ void soft_pv(const f32x16& st, const short8* v,
                                               f32x16& o0, f32x16& o1, float& lsum) {
  float ls = 0.f;
  unsigned cpk[8];
#pragma unroll
  for (int q2 = 0; q2 < 4; q2++) {
    float e0 = fexp2(st[4 * q2]),     e1 = fexp2(st[4 * q2 + 1]);
    float e2 = fexp2(st[4 * q2 + 2]), e3 = fexp2(st[4 * q2 + 3]);
    ls += (e0 + e1) + (e2 + e3);
    cpk[2 * q2]     = cvt_pk_bf16(e0, e1);
    cpk[2 * q2 + 1] = cvt_pk_bf16(e2, e3);
  }
  lsum += ls;
  unsigned w00 = cpk[0], w02 = cpk[2];
  asm volatile("v_permlane32_swap_b32 %0, %1" : "+v"(w00), "+v"(w02));
  unsigned w01 = cpk[1], w03 = cpk[3];
  asm volatile("v_permlane32_swap_b32 %0, %1" : "+v"(w01), "+v"(w03));
  unsigned w10 = cpk[4], w12 = cpk[6];
  asm volatile("v_permlane32_swap_b32 %0, %1" : "+v"(w10), "+v"(w12));
  unsigned w11 = cpk[5], w13 = cpk[7];
  asm volatile("v_permlane32_swap_b32 %0, %1" : "+v"(w11), "+v"(w13));
  union { unsigned u[4]; short8 s; } u0, u1;
  u0.u[0] = w00; u0.u[1] = w01; u0.u[2] = w02; u0.u[3] = w03;
  u1.u[0] = w10; u1.u[1] = w11; u1.u[2] = w12; u1.u[3] = w13;
  __builtin_amdgcn_s_setprio(1);
  o0 = __builtin_amdgcn_mfma_f32_32x32x16_bf16(u0.s, v[0], o0, 0, 0, 0);
  o0 = __builtin_amdgcn_mfma_f32_32x32x16_bf16(u1.s, v[1], o0, 0, 0, 0);
  o1 = __builtin_amdgcn_mfma_f32_32x32x16_bf16(u0.s, v[2], o1, 0, 0, 0);
  o1 = __builtin_amdgcn_mfma_f32_32x32x16_bf16(u1.s, v[3], o1, 0, 0, 0);
  __builtin_amdgcn_s_setprio(0);
}

// ---------- Flash attention: 64 q-rows/wave, VALU lsum, 2-way KV split ----------
__global__ __launch_bounds__(256, 2) void attn(const short* __restrict__ Qf, const short* __restrict__ Kf,
                                               const short* __restrict__ Vf,
                                               short* __restrict__ Op, float* __restrict__ lp) {
  __shared__ short Ks[2][4096];
  __shared__ short Vs[2][4096];
  int bh = blockIdx.x;
  int ch = blockIdx.z;
  int t = threadIdx.x;
  int wv = t >> 6, lane = t & 63;
  int c = lane & 31, hi = lane >> 5;
  int q0 = blockIdx.y * 256 + wv * 64;       // this wave: q0..q0+63
  const int nkb2 = N_ / (NCH * 64);          // 32 iters of 64 kv
  int kb0 = ch * (N_ / (NCH * 32));          // in 32-kv block units

  const short* QbA = Qf + ((size_t)(bh * 128 + (q0 >> 5)) * 4) * 512 + lane * 8;
  const short* Kg = Kf + ((size_t)(bh * 128 + kb0) * 4) * 512 + t * 8;
  const short* Vg = Vf + ((size_t)(bh * 128 + kb0) * 4) * 512 + t * 8;

  short8 qA[4], qB[4];
#pragma unroll
  for (int f = 0; f < 4; f++) qA[f] = *(const short8*)(QbA + f * 512);
#pragma unroll
  for (int f = 0; f < 4; f++) qB[f] = *(const short8*)(QbA + (4 + f) * 512);

  const f32x16 z0 = zero16();
  f32x16 oA0 = z0, oA1 = z0;
  f32x16 oB0 = z0, oB1 = z0;
  float lsA = 0.f, lsB = 0.f;

  gload_lds16(Kg,        &Ks[0][t * 8]);
  gload_lds16(Kg + 2048, &Ks[0][2048 + t * 8]);
  gload_lds16(Vg,        &Vs[0][t * 8]);
  gload_lds16(Vg + 2048, &Vs[0][2048 + t * 8]);
  __syncthreads();

  int buf = 0;
  for (int it = 0; it < nkb2; ++it) {
    if (it + 1 < nkb2) {
      const short* Kn = Kg + (size_t)(it + 1) * 4096;
      const short* Vn = Vg + (size_t)(it + 1) * 4096;
      gload_lds16(Kn,        &Ks[buf ^ 1][t * 8]);
      gload_lds16(Kn + 2048, &Ks[buf ^ 1][2048 + t * 8]);
      gload_lds16(Vn,        &Vs[buf ^ 1][t * 8]);
      gload_lds16(Vn + 2048, &Vs[buf ^ 1][2048 + t * 8]);
    }
#pragma unroll
    for (int s = 0; s < 2; s++) {
      short8 kf[4], vf[4];
#pragma unroll
      for (int f = 0; f < 4; f++) kf[f] = *(const short8*)&Ks[buf][s * 2048 + f * 512 + lane * 8];
#pragma unroll
      for (int f = 0; f < 4; f++) vf[f] = *(const short8*)&Vs[buf][s * 2048 + f * 512 + lane * 8];
      f32x16 stA = qk4(kf, qA, z0);
      f32x16 stB = qk4(kf, qB, z0);
      soft_pv(stA, vf, oA0, oA1, lsA);
      soft_pv(stB, vf, oB0, oB1, lsB);
    }
    __syncthreads();
    buf ^= 1;
  }

  float ltA = lsA + __shfl_xor(lsA, 32);
  float ltB = lsB + __shfl_xor(lsB, 32);
  float* lrow = lp + ((size_t)ch * 16 + bh) * N_ + q0;
  short* obase = Op + ((size_t)ch * 16 + bh) * N_ * D_;
  if (hi == 0) {
    lrow[c] = ltA;
    lrow[32 + c] = ltB;
  }
#pragma unroll
  for (int r = 0; r < 16; r++) {
    int ql = (r & 3) + 8 * (r >> 2) + 4 * hi;
    size_t nA = (size_t)(q0 + ql) * D_;
    size_t nB = (size_t)(q0 + 32 + ql) * D_;
    obase[nA + c]      = (short)f2bf(oA0[r]);
    obase[nA + 32 + c] = (short)f2bf(oA1[r]);
    obase[nB + c]      = (short)f2bf(oB0[r]);
    obase[nB + 32 + c] = (short)f2bf(oB1[r]);
  }
}

// ---------- launch ----------
extern "C" void kernel_launch(void* const* d_in, const int* in_sizes, int n_in,
                              void* d_out, int out_size, void* d_ws, size_t ws_size,
                              hipStream_t stream) {
  const float* x     = (const float*)d_in[0];
  const float* Wqkv  = (const float*)d_in[1];
  const float* bqkv  = (const float*)d_in[2];
  const float* Wproj = (const float*)d_in[3];
  const float* bproj = (const float*)d_in[4];
  float* out = (float*)d_out;
  char* ws = (char*)d_ws;

  // persistent region
  const size_t off_wprjb = 0;          // 524,288
  const size_t off_tab   = 524288;     // 1,048,576
  const size_t off_q     = 1572864;    // 8,388,608
  const size_t off_k     = 9961472;    // 8,388,608
  const size_t off_vt    = 18350080;   // 8,388,608 -> ends 26,738,688
  // transient
  const size_t off_xb    = 35127296;   // 8,388,608
  const size_t off_wqkvb = 43515904;   // 1,572,864
  // attn-phase partials (alias nothing live)
  const size_t off_op    = 45088768;   // 2*16*4096*64*2 = 16,777,216
  const size_t off_l     = 68681728;   // 2*16*4096*4    =    524,288
  if (ws_size < 70254592) return;

  short* xb    = (short*)(ws + off_xb);
  short* wqkvb = (short*)(ws + off_wqkvb);
  short* wprjb = (short*)(ws + off_wprjb);
  short* Qfp   = (short*)(ws + off_q);
  short* Kfp   = (short*)(ws + off_k);
  short* Vfp   = (short*)(ws + off_vt);
  float2* tab  = (float2*)(ws + off_tab);
  short* Opp   = (short*)(ws + off_op);
  float* lpp   = (float*)(ws + off_l);

  prep<<<dim3(5632), dim3(256), 0, stream>>>(x, Wqkv, Wproj, xb, wqkvb, wprjb, tab);

  gemm_qkv<<<dim3(64, 12), dim3(256), 0, stream>>>(xb, wqkvb, bqkv, tab, Qfp, Kfp, Vfp);

  attn<<<dim3(16, 16, NCH), dim3(256), 0, stream>>>(Qfp, Kfp, Vfp, Opp, lpp);

  gemm_proj<<<dim3(128, 4), dim3(256), 0, stream>>>(Opp, lpp, wprjb, bproj, out);
}